// Round 1
// baseline (12011.470 us; speedup 1.0000x reference)
//
#include <hip/hip_runtime.h>
#include <hip/hip_bf16.h>
#include <math.h>

using f32x4 = __attribute__((ext_vector_type(4))) float;
using s16x8 = __attribute__((ext_vector_type(8))) short;
typedef unsigned short u16;

__device__ __forceinline__ float bf2f(u16 u){
  union { unsigned int i; float f; } v; v.i = ((unsigned int)u) << 16; return v.f;
}
__device__ __forceinline__ u16 f2bf(float f){
  union { float f; unsigned int i; } v; v.f = f;
  unsigned int x = v.i;
  return (u16)((x + 0x7fffu + ((x >> 16) & 1u)) >> 16);
}
__device__ __forceinline__ float sigm(float x){ return 1.0f/(1.0f + expf(-x)); }

// ---------------- small utility kernels ----------------
__global__ void k_zero(float* __restrict__ p, long n){
  long i = (long)blockIdx.x*blockDim.x + threadIdx.x;
  long st = (long)gridDim.x*blockDim.x;
  for (; i < n; i += st) p[i] = 0.0f;
}

__global__ void k_cast_bf16(const float* __restrict__ src, u16* __restrict__ dst, long n){
  long i = ((long)blockIdx.x*blockDim.x + threadIdx.x)*4;
  long st = (long)gridDim.x*blockDim.x*4;
  for (; i < n; i += st){
    float4 v = *(const float4*)(src + i);
    *(ushort4*)(dst + i) = make_ushort4(f2bf(v.x), f2bf(v.y), f2bf(v.z), f2bf(v.w));
  }
}

__global__ void k_addv(const float* __restrict__ a, const float* __restrict__ b,
                       float* __restrict__ d, int n){
  int i = blockIdx.x*blockDim.x + threadIdx.x;
  if (i < n) d[i] = a[i] + b[i];
}

// cnn_w (512,512,2) -> Wconv_bf [512][1024] = [W0 | W1]
__global__ void k_repack_conv(const float* __restrict__ w, u16* __restrict__ dst){
  int i = blockIdx.x*256 + threadIdx.x; // 0..262143
  int o = i >> 9, ii = i & 511;
  dst[(size_t)o*1024 + ii]       = f2bf(w[((size_t)o*512 + ii)*2 + 0]);
  dst[(size_t)o*1024 + 512 + ii] = f2bf(w[((size_t)o*512 + ii)*2 + 1]);
}

// dec_Wih (4096,1536), dec_Whh (4096,1024) -> Wcat [4096][2048] = [Wih[:, :1024] | Whh], Wy [4096][512]
__global__ void k_build_wdec(const float* __restrict__ dWih, const float* __restrict__ dWhh,
                             u16* __restrict__ Wcat, u16* __restrict__ Wy){
  int r = blockIdx.x; // 0..4095
  for (int c = threadIdx.x; c < 1024; c += 256){
    Wcat[(size_t)r*2048 + c]        = f2bf(dWih[(size_t)r*1536 + c]);
    Wcat[(size_t)r*2048 + 1024 + c] = f2bf(dWhh[(size_t)r*1024 + c]);
  }
  for (int c = threadIdx.x; c < 512; c += 256)
    Wy[(size_t)r*512 + c] = f2bf(dWih[(size_t)r*1536 + 1024 + c]);
}

// gather src embeddings into conv A: Aconv[s*64+b] = [X[s,b,:] | X[s+1,b,:]] bf16 (X[48]=0)
__global__ void k_gather_src(const int* __restrict__ ids, const float* __restrict__ emb,
                             u16* __restrict__ Aconv){
  int s = blockIdx.x;  // 0..48
  int b = blockIdx.y;
  int e = threadIdx.x*4; // block 128 -> 512
  float4 v = make_float4(0.f,0.f,0.f,0.f);
  if (s < 48){ int id = ids[s*64 + b]; v = *(const float4*)(emb + (size_t)id*512 + e); }
  ushort4 u = make_ushort4(f2bf(v.x), f2bf(v.y), f2bf(v.z), f2bf(v.w));
  if (s < 48) *(ushort4*)(Aconv + ((size_t)(s*64 + b))*1024 + e) = u;
  if (s >= 1) *(ushort4*)(Aconv + ((size_t)((s-1)*64 + b))*1024 + 512 + e) = u;
}

__global__ void k_gather_y(const int* __restrict__ ids, const float* __restrict__ emb,
                           u16* __restrict__ Y){
  int t = blockIdx.x; int b = blockIdx.y; int e = threadIdx.x*4;
  int id = ids[t*64 + b];
  float4 v = *(const float4*)(emb + (size_t)id*512 + e);
  *(ushort4*)(Y + ((size_t)(t*64 + b))*512 + e) = make_ushort4(f2bf(v.x), f2bf(v.y), f2bf(v.z), f2bf(v.w));
}

// ---------------- universal MFMA GEMM ----------------
// C[M,N] = A[M,K] @ W[N,K]^T (+G)(+bias)(tanh?), 64x64 tile / block of 256 (4 waves)
// Dual A-source (split at ksplit, multiples of 64). A rows = out rows (m0=blockIdx.x*64).
template<bool A_F32, bool OUT_BF16, bool TANH>
__global__ __launch_bounds__(256) void k_gemm(
    const void* __restrict__ A0, long lda0,
    const void* __restrict__ A1, long lda1, int ksplit,
    const u16* __restrict__ W, int K,
    void* __restrict__ Out, long ldc, long out_off,
    const float* __restrict__ bias,
    const u16* __restrict__ G, long g_row_off, int ldg)
{
  __shared__ __align__(16) u16 As[64][72];
  __shared__ __align__(16) u16 Ws[64][72];
  const int t = threadIdx.x;
  const int m0 = blockIdx.x*64, n0 = blockIdx.y*64;
  const int w = t >> 6, l = t & 63, lr = l & 15, lh = l >> 4;
  const int sr = t >> 2, sk = (t & 3) << 4;

  f32x4 acc[4] = {{0,0,0,0},{0,0,0,0},{0,0,0,0},{0,0,0,0}};

  for (int kc = 0; kc < K; kc += 64){
    { // stage W (always bf16)
      const u16* wp = W + (size_t)(n0 + sr)*K + kc + sk;
      *(s16x8*)&Ws[sr][sk]     = *(const s16x8*)wp;
      *(s16x8*)&Ws[sr][sk + 8] = *(const s16x8*)(wp + 8);
    }
    { // stage A
      const void* Asrc; long lda; int kb;
      if (kc < ksplit){ Asrc = A0; lda = lda0; kb = kc; }
      else            { Asrc = A1; lda = lda1; kb = kc - ksplit; }
      if (A_F32){
        const float* ap = (const float*)Asrc + (size_t)(m0 + sr)*lda + kb + sk;
        float4 v0 = *(const float4*)ap,       v1 = *(const float4*)(ap + 4);
        float4 v2 = *(const float4*)(ap + 8), v3 = *(const float4*)(ap + 12);
        *(ushort4*)&As[sr][sk]      = make_ushort4(f2bf(v0.x), f2bf(v0.y), f2bf(v0.z), f2bf(v0.w));
        *(ushort4*)&As[sr][sk + 4]  = make_ushort4(f2bf(v1.x), f2bf(v1.y), f2bf(v1.z), f2bf(v1.w));
        *(ushort4*)&As[sr][sk + 8]  = make_ushort4(f2bf(v2.x), f2bf(v2.y), f2bf(v2.z), f2bf(v2.w));
        *(ushort4*)&As[sr][sk + 12] = make_ushort4(f2bf(v3.x), f2bf(v3.y), f2bf(v3.z), f2bf(v3.w));
      } else {
        const u16* ap = (const u16*)Asrc + (size_t)(m0 + sr)*lda + kb + sk;
        *(s16x8*)&As[sr][sk]     = *(const s16x8*)ap;
        *(s16x8*)&As[sr][sk + 8] = *(const s16x8*)(ap + 8);
      }
    }
    __syncthreads();
    #pragma unroll
    for (int kk = 0; kk < 64; kk += 32){
      s16x8 a = *(const s16x8*)&As[w*16 + lr][kk + lh*8];
      #pragma unroll
      for (int ct = 0; ct < 4; ++ct){
        s16x8 bfr = *(const s16x8*)&Ws[ct*16 + lr][kk + lh*8];
        acc[ct] = __builtin_amdgcn_mfma_f32_16x16x32_bf16(a, bfr, acc[ct], 0, 0, 0);
      }
    }
    __syncthreads();
  }
  #pragma unroll
  for (int ct = 0; ct < 4; ++ct){
    #pragma unroll
    for (int rr = 0; rr < 4; ++rr){
      long row = m0 + w*16 + lh*4 + rr;
      long col = n0 + ct*16 + lr;
      float v = acc[ct][rr];
      if (G)    v += bf2f(G[(g_row_off + row)*(long)ldg + col]);
      if (bias) v += bias[col];
      if (TANH) v = tanhf(v);
      long oi = out_off + row*ldc + col;
      if (OUT_BF16) ((u16*)Out)[oi] = f2bf(v);
      else          ((float*)Out)[oi] = v;
    }
  }
}

// ---------------- LSTM activations ----------------
__global__ void k_enc_act(const float* __restrict__ gates_f, const float* __restrict__ gates_b,
                          float* __restrict__ h_f, float* __restrict__ c_f,
                          float* __restrict__ h_b, float* __restrict__ c_b,
                          u16* __restrict__ Aatt, int s)
{
  int dir = blockIdx.y;
  int base = blockIdx.x*256 + threadIdx.x; // 0..16383
  const float* g = dir ? gates_b : gates_f;
  float* h = dir ? h_b : h_f;
  float* c = dir ? c_b : c_f;
  int time = dir ? (47 - s) : s;
  for (int rep = 0; rep < 4; ++rep){
    int idx = base + rep*16384;  // 0..65535
    int b = idx >> 10, j = idx & 1023;
    float gi = g[b*4096 + j],        gf = g[b*4096 + 1024 + j];
    float gg = g[b*4096 + 2048 + j], go = g[b*4096 + 3072 + j];
    float cn = sigm(gf)*c[idx] + sigm(gi)*tanhf(gg);
    float hn = sigm(go)*tanhf(cn);
    c[idx] = cn; h[idx] = hn;
    Aatt[((size_t)b*48 + time)*2048 + dir*1024 + j] = f2bf(hn);
  }
}

__global__ void k_cast_hc(const float* __restrict__ h_f, const float* __restrict__ h_b,
                          u16* __restrict__ Ahc){
  int i = blockIdx.x*256 + threadIdx.x; // 131072
  int b = i >> 11, j = i & 2047;
  float v = (j < 1024) ? h_f[b*1024 + j] : h_b[b*1024 + j - 1024];
  Ahc[i] = f2bf(v);
}

// decoder: LSTM activation + attention (one block per batch row)
__global__ __launch_bounds__(256) void k_dec_act_attn(
    const float* __restrict__ gates, float* __restrict__ hdec, float* __restrict__ cdec,
    const float* __restrict__ encproj, const u16* __restrict__ Aatt,
    float* __restrict__ a_t)
{
  __shared__ float hs[1024];
  __shared__ float ew[48];
  __shared__ float smax, sinv;
  int b = blockIdx.x;
  int t = threadIdx.x;
  for (int j = t; j < 1024; j += 256){
    float gi = gates[b*4096 + j],        gf = gates[b*4096 + 1024 + j];
    float gg = gates[b*4096 + 2048 + j], go = gates[b*4096 + 3072 + j];
    float cn = sigm(gf)*cdec[b*1024 + j] + sigm(gi)*tanhf(gg);
    float hn = sigm(go)*tanhf(cn);
    cdec[b*1024 + j] = cn; hdec[b*1024 + j] = hn; hs[j] = hn;
  }
  __syncthreads();
  int w = t >> 6, l = t & 63;
  for (int s = w; s < 48; s += 4){
    const float* ep = encproj + ((size_t)b*48 + s)*1024;
    float p = 0.f;
    for (int i = l; i < 1024; i += 64) p += hs[i]*ep[i];
    for (int d = 32; d >= 1; d >>= 1) p += __shfl_xor(p, d, 64);
    if (l == 0) ew[s] = p;
  }
  __syncthreads();
  if (t == 0){
    float m = ew[0];
    for (int s = 1; s < 48; ++s) m = fmaxf(m, ew[s]);
    smax = m;
  }
  __syncthreads();
  if (t < 48) ew[t] = expf(ew[t] - smax);
  __syncthreads();
  if (t == 0){
    float su = 0.f; for (int s = 0; s < 48; ++s) su += ew[s];
    sinv = 1.0f/su;
  }
  __syncthreads();
  for (int d = t; d < 2048; d += 256){
    float accd = 0.f;
    for (int s = 0; s < 48; ++s)
      accd += ew[s]*bf2f(Aatt[((size_t)b*48 + s)*2048 + d]);
    a_t[b*2048 + d] = accd*sinv;
  }
}

// ---------------- fused vocab GEMM + online logsumexp ----------------
#define VNS 25
__global__ __launch_bounds__(256) void k_vocab_lse(
    const u16* __restrict__ Cbf, const u16* __restrict__ Wv, float2* __restrict__ partials)
{
  __shared__ __align__(16) u16 As[64][136];
  __shared__ __align__(16) u16 Ws[64][136];
  int rb = blockIdx.x, sp = blockIdx.y;
  int m0 = rb*64;
  int t = threadIdx.x, w = t >> 6, l = t & 63, lr = l & 15, lh = l >> 4;
  int sr = t >> 2, sk = (t & 3) << 5;
  float mrun[4] = {-INFINITY, -INFINITY, -INFINITY, -INFINITY};
  float srun[4] = {0.f, 0.f, 0.f, 0.f};

  for (int nt = 0; nt < 20; ++nt){
    int n0 = sp*1280 + nt*64;
    f32x4 acc[4] = {{0,0,0,0},{0,0,0,0},{0,0,0,0},{0,0,0,0}};
    for (int kc = 0; kc < 1024; kc += 128){
      const u16* ap = Cbf + (size_t)(m0 + sr)*1024 + kc + sk;
      const u16* wp = Wv  + (size_t)(n0 + sr)*1024 + kc + sk;
      #pragma unroll
      for (int q = 0; q < 4; ++q){
        *(s16x8*)&As[sr][sk + q*8] = *(const s16x8*)(ap + q*8);
        *(s16x8*)&Ws[sr][sk + q*8] = *(const s16x8*)(wp + q*8);
      }
      __syncthreads();
      #pragma unroll
      for (int kk = 0; kk < 128; kk += 32){
        s16x8 a = *(const s16x8*)&As[w*16 + lr][kk + lh*8];
        #pragma unroll
        for (int ct = 0; ct < 4; ++ct){
          s16x8 bfr = *(const s16x8*)&Ws[ct*16 + lr][kk + lh*8];
          acc[ct] = __builtin_amdgcn_mfma_f32_16x16x32_bf16(a, bfr, acc[ct], 0, 0, 0);
        }
      }
      __syncthreads();
    }
    #pragma unroll
    for (int rr = 0; rr < 4; ++rr){
      float tm = fmaxf(fmaxf(acc[0][rr], acc[1][rr]), fmaxf(acc[2][rr], acc[3][rr]));
      for (int d = 1; d < 16; d <<= 1) tm = fmaxf(tm, __shfl_xor(tm, d, 64));
      float ts = expf(acc[0][rr] - tm) + expf(acc[1][rr] - tm)
               + expf(acc[2][rr] - tm) + expf(acc[3][rr] - tm);
      for (int d = 1; d < 16; d <<= 1) ts += __shfl_xor(ts, d, 64);
      if (tm > mrun[rr]){ srun[rr] = srun[rr]*expf(mrun[rr] - tm) + ts; mrun[rr] = tm; }
      else srun[rr] += ts*expf(tm - mrun[rr]);
    }
  }
  if (lr == 0){
    #pragma unroll
    for (int rr = 0; rr < 4; ++rr){
      long row = m0 + w*16 + lh*4 + rr;
      partials[row*VNS + sp] = make_float2(mrun[rr], srun[rr]);
    }
  }
}

__global__ void k_lse(const float2* __restrict__ partials, float* __restrict__ lse){
  int r = blockIdx.x*256 + threadIdx.x;
  if (r >= 3008) return;
  float m = -INFINITY, s = 0.f;
  for (int i = 0; i < VNS; ++i){
    float2 p = partials[r*VNS + i];
    if (p.x > m){ s = s*expf(m - p.x) + p.y; m = p.x; }
    else s += p.y*expf(p.x - m);
  }
  lse[r] = m + logf(s);
}

__global__ __launch_bounds__(256) void k_gold(const float* __restrict__ combined,
                                              const float* __restrict__ Wv,
                                              const int* __restrict__ tgt,
                                              float* __restrict__ gold){
  int w = threadIdx.x >> 6, l = threadIdx.x & 63;
  int r = blockIdx.x*4 + w; // 0..3007
  int tt = r >> 6, b = r & 63;
  int gid = tgt[(tt + 1)*64 + b];
  const float* cp = combined + (size_t)r*1024;
  const float* wp = Wv + (size_t)gid*1024;
  float p = 0.f;
  for (int i = l; i < 1024; i += 64) p += cp[i]*wp[i];
  for (int d = 32; d >= 1; d >>= 1) p += __shfl_xor(p, d, 64);
  if (l == 0) gold[r] = p;
}

__global__ void k_final(const float* __restrict__ gold, const float* __restrict__ lse,
                        const int* __restrict__ tgt, float* __restrict__ out){
  int b = threadIdx.x;
  if (b >= 64) return;
  float acc = 0.f;
  for (int t = 0; t < 47; ++t){
    int gid = tgt[(t + 1)*64 + b];
    if (gid != 0) acc += gold[t*64 + b] - lse[t*64 + b];
  }
  out[b] = acc;
}

// ---------------- host ----------------
extern "C" void kernel_launch(void* const* d_in, const int* in_sizes, int n_in,
                              void* d_out, int out_size, void* d_ws, size_t ws_size,
                              hipStream_t stream)
{
  (void)in_sizes; (void)n_in; (void)out_size; (void)ws_size;
  const int*   src_ids = (const int*)d_in[0];
  const int*   tgt_ids = (const int*)d_in[1];
  const float* src_emb = (const float*)d_in[3];
  const float* tgt_emb = (const float*)d_in[4];
  const float* cnn_w   = (const float*)d_in[5];
  const float* cnn_b   = (const float*)d_in[6];
  const float* eWih_f  = (const float*)d_in[7];
  const float* eWhh_f  = (const float*)d_in[8];
  const float* ebih_f  = (const float*)d_in[9];
  const float* ebhh_f  = (const float*)d_in[10];
  const float* eWih_b  = (const float*)d_in[11];
  const float* eWhh_b  = (const float*)d_in[12];
  const float* ebih_b  = (const float*)d_in[13];
  const float* ebhh_b  = (const float*)d_in[14];
  const float* dWih    = (const float*)d_in[15];
  const float* dWhh    = (const float*)d_in[16];
  const float* dbih    = (const float*)d_in[17];
  const float* dbhh    = (const float*)d_in[18];
  const float* Wh      = (const float*)d_in[19];
  const float* Wc      = (const float*)d_in[20];
  const float* Watt    = (const float*)d_in[21];
  const float* Wcomb   = (const float*)d_in[22];
  const float* Wvocab  = (const float*)d_in[23];

  char* ws = (char*)d_ws;
  size_t off = 0;
  auto alloc = [&](size_t bytes)->char*{
    char* p = ws + off;
    off = (off + bytes + 255) & ~(size_t)255;
    return p;
  };

  u16* Wconv_bf = (u16*)alloc((size_t)512*1024*2);
  u16* Wih_f_bf = (u16*)alloc((size_t)4096*512*2);
  u16* Wih_b_bf = (u16*)alloc((size_t)4096*512*2);
  u16* Whh_f_bf = (u16*)alloc((size_t)4096*1024*2);
  u16* Whh_b_bf = (u16*)alloc((size_t)4096*1024*2);
  u16* Wdec_bf  = (u16*)alloc((size_t)4096*2048*2);
  u16* WdecY_bf = (u16*)alloc((size_t)4096*512*2);
  u16* Wh_bf    = (u16*)alloc((size_t)1024*2048*2);
  u16* Wc_bf    = (u16*)alloc((size_t)1024*2048*2);
  u16* Watt_bf  = (u16*)alloc((size_t)1024*2048*2);
  u16* Wcomb_bf = (u16*)alloc((size_t)1024*3072*2);
  u16* Wv_bf    = (u16*)alloc((size_t)32000*1024*2);
  float* benc_f = (float*)alloc(4096*4);
  float* benc_b = (float*)alloc(4096*4);
  float* bdec   = (float*)alloc(4096*4);
  u16* Aconv    = (u16*)alloc((size_t)3072*1024*2);
  u16* Xc       = (u16*)alloc((size_t)3072*512*2);
  u16* Gf       = (u16*)alloc((size_t)3072*4096*2);
  u16* Gb       = (u16*)alloc((size_t)3072*4096*2);
  u16* Ybf      = (u16*)alloc((size_t)3008*512*2);
  u16* Gy       = (u16*)alloc((size_t)3008*4096*2);
  u16* Aatt     = (u16*)alloc((size_t)3072*2048*2);
  float* encproj= (float*)alloc((size_t)3072*1024*4);
  float* h_f    = (float*)alloc((size_t)65536*4);
  float* c_f    = (float*)alloc((size_t)65536*4);
  float* h_b    = (float*)alloc((size_t)65536*4);
  float* c_b    = (float*)alloc((size_t)65536*4);
  float* zbuf   = (float*)alloc((size_t)65536*4);
  float* gates_f= (float*)alloc((size_t)64*4096*4);
  float* gates_b= (float*)alloc((size_t)64*4096*4);
  float* gates_d= (float*)alloc((size_t)64*4096*4);
  float* hdec   = (float*)alloc((size_t)65536*4);
  float* cdec   = (float*)alloc((size_t)65536*4);
  float* a_t    = (float*)alloc((size_t)64*2048*4);
  u16* Ahc      = (u16*)alloc((size_t)64*2048*2);
  float* combined=(float*)alloc((size_t)3008*1024*4);
  u16* Cbf      = (u16*)alloc((size_t)3008*1024*2);
  float2* partials=(float2*)alloc((size_t)3008*VNS*8);
  float* lse    = (float*)alloc(3008*4);
  float* gold   = (float*)alloc(3008*4);

  // zero states (h_f,c_f,h_b,c_b,zbuf contiguous)
  k_zero<<<256, 256, 0, stream>>>(h_f, (long)5*65536);

  auto cgrid = [](long n)->int{ long g = (n/4 + 255)/256; return (int)(g > 1024 ? 1024 : g); };
  k_cast_bf16<<<cgrid(4096*512), 256, 0, stream>>>(eWih_f, Wih_f_bf, (long)4096*512);
  k_cast_bf16<<<cgrid(4096*512), 256, 0, stream>>>(eWih_b, Wih_b_bf, (long)4096*512);
  k_cast_bf16<<<cgrid(4096*1024), 256, 0, stream>>>(eWhh_f, Whh_f_bf, (long)4096*1024);
  k_cast_bf16<<<cgrid(4096*1024), 256, 0, stream>>>(eWhh_b, Whh_b_bf, (long)4096*1024);
  k_cast_bf16<<<cgrid(1024*2048), 256, 0, stream>>>(Wh, Wh_bf, (long)1024*2048);
  k_cast_bf16<<<cgrid(1024*2048), 256, 0, stream>>>(Wc, Wc_bf, (long)1024*2048);
  k_cast_bf16<<<cgrid(1024*2048), 256, 0, stream>>>(Watt, Watt_bf, (long)1024*2048);
  k_cast_bf16<<<cgrid(1024*3072), 256, 0, stream>>>(Wcomb, Wcomb_bf, (long)1024*3072);
  k_cast_bf16<<<cgrid((long)32000*1024), 256, 0, stream>>>(Wvocab, Wv_bf, (long)32000*1024);

  k_addv<<<16, 256, 0, stream>>>(ebih_f, ebhh_f, benc_f, 4096);
  k_addv<<<16, 256, 0, stream>>>(ebih_b, ebhh_b, benc_b, 4096);
  k_addv<<<16, 256, 0, stream>>>(dbih, dbhh, bdec, 4096);

  k_repack_conv<<<1024, 256, 0, stream>>>(cnn_w, Wconv_bf);
  k_build_wdec<<<4096, 256, 0, stream>>>(dWih, dWhh, Wdec_bf, WdecY_bf);

  k_gather_src<<<dim3(49, 64), 128, 0, stream>>>(src_ids, src_emb, Aconv);
  k_gather_y<<<dim3(47, 64), 128, 0, stream>>>(tgt_ids, tgt_emb, Ybf);

  // conv: Xc = Aconv @ Wconv^T + cnn_b  (bf16 out)
  k_gemm<false, true, false><<<dim3(48, 8), 256, 0, stream>>>(
      Aconv, 1024, Aconv, 1024, 1024, Wconv_bf, 1024, Xc, 512, 0, cnn_b, nullptr, 0, 0);
  // G = Xc @ Wih^T + bias
  k_gemm<false, true, false><<<dim3(48, 64), 256, 0, stream>>>(
      Xc, 512, Xc, 512, 512, Wih_f_bf, 512, Gf, 4096, 0, benc_f, nullptr, 0, 0);
  k_gemm<false, true, false><<<dim3(48, 64), 256, 0, stream>>>(
      Xc, 512, Xc, 512, 512, Wih_b_bf, 512, Gb, 4096, 0, benc_b, nullptr, 0, 0);
  k_gemm<false, true, false><<<dim3(47, 64), 256, 0, stream>>>(
      Ybf, 512, Ybf, 512, 512, WdecY_bf, 512, Gy, 4096, 0, bdec, nullptr, 0, 0);

  // encoder: 48 steps, fwd + bwd
  for (int s = 0; s < 48; ++s){
    k_gemm<true, false, false><<<dim3(1, 64), 256, 0, stream>>>(
        h_f, 1024, h_f, 1024, 1024, Whh_f_bf, 1024, gates_f, 4096, 0,
        nullptr, Gf, (long)s*64, 4096);
    k_gemm<true, false, false><<<dim3(1, 64), 256, 0, stream>>>(
        h_b, 1024, h_b, 1024, 1024, Whh_b_bf, 1024, gates_b, 4096, 0,
        nullptr, Gb, (long)(47 - s)*64, 4096);
    k_enc_act<<<dim3(64, 2), 256, 0, stream>>>(gates_f, gates_b, h_f, c_f, h_b, c_b, Aatt, s);
  }

  k_cast_hc<<<512, 256, 0, stream>>>(h_f, h_b, Ahc);
  k_gemm<false, false, false><<<dim3(1, 16), 256, 0, stream>>>(
      Ahc, 2048, Ahc, 2048, 2048, Wh_bf, 2048, hdec, 1024, 0, nullptr, nullptr, 0, 0);
  k_gemm<false, false, false><<<dim3(1, 16), 256, 0, stream>>>(
      Ahc, 2048, Ahc, 2048, 2048, Wc_bf, 2048, cdec, 1024, 0, nullptr, nullptr, 0, 0);
  k_gemm<false, false, false><<<dim3(48, 16), 256, 0, stream>>>(
      Aatt, 2048, Aatt, 2048, 2048, Watt_bf, 2048, encproj, 1024, 0, nullptr, nullptr, 0, 0);

  // decoder: 47 steps
  for (int t = 0; t < 47; ++t){
    const float* oprev = (t == 0) ? zbuf : (combined + (size_t)(t - 1)*65536);
    k_gemm<true, false, false><<<dim3(1, 64), 256, 0, stream>>>(
        oprev, 1024, hdec, 1024, 1024, Wdec_bf, 2048, gates_d, 4096, 0,
        nullptr, Gy, (long)t*64, 4096);
    k_dec_act_attn<<<64, 256, 0, stream>>>(gates_d, hdec, cdec, encproj, Aatt, a_t);
    k_gemm<true, false, true><<<dim3(1, 16), 256, 0, stream>>>(
        a_t, 2048, hdec, 1024, 2048, Wcomb_bf, 3072, combined, 1024, (long)t*65536,
        nullptr, nullptr, 0, 0);
  }

  k_cast_bf16<<<1024, 256, 0, stream>>>(combined, Cbf, (long)3008*1024);
  k_vocab_lse<<<dim3(47, VNS), 256, 0, stream>>>(Cbf, Wv_bf, partials);
  k_lse<<<12, 256, 0, stream>>>(partials, lse);
  k_gold<<<752, 256, 0, stream>>>(combined, Wvocab, tgt_ids, gold);
  k_final<<<1, 64, 0, stream>>>(gold, lse, tgt_ids, (float*)d_out);
}

// Round 2
// 8919.662 us; speedup vs baseline: 1.3466x; 1.3466x over previous
//
#include <hip/hip_runtime.h>
#include <hip/hip_bf16.h>
#include <math.h>

using f32x4 = __attribute__((ext_vector_type(4))) float;
using s16x8 = __attribute__((ext_vector_type(8))) short;
typedef unsigned short u16;

__device__ __forceinline__ float bf2f(u16 u){
  union { unsigned int i; float f; } v; v.i = ((unsigned int)u) << 16; return v.f;
}
__device__ __forceinline__ u16 f2bf(float f){
  union { float f; unsigned int i; } v; v.f = f;
  unsigned int x = v.i;
  return (u16)((x + 0x7fffu + ((x >> 16) & 1u)) >> 16);
}
__device__ __forceinline__ float sigm(float x){ return 1.0f/(1.0f + expf(-x)); }

// grid barrier: monotonic counter, agent scope. All blocks call it the same
// number of times; counter zeroed in-stream before each persistent kernel.
__device__ __forceinline__ void gbar(int* cnt, int nb, int& gen){
  __syncthreads();
  if (threadIdx.x == 0){
    ++gen;
    __threadfence();
    __hip_atomic_fetch_add(cnt, 1, __ATOMIC_RELEASE, __HIP_MEMORY_SCOPE_AGENT);
    while (__hip_atomic_load(cnt, __ATOMIC_ACQUIRE, __HIP_MEMORY_SCOPE_AGENT) < nb*gen)
      __builtin_amdgcn_s_sleep(2);
    __threadfence();
  }
  __syncthreads();
}

// ---------------- small utility kernels ----------------
__global__ void k_zero(float* __restrict__ p, long n){
  long i = (long)blockIdx.x*blockDim.x + threadIdx.x;
  long st = (long)gridDim.x*blockDim.x;
  for (; i < n; i += st) p[i] = 0.0f;
}

__global__ void k_cast_bf16(const float* __restrict__ src, u16* __restrict__ dst, long n){
  long i = ((long)blockIdx.x*blockDim.x + threadIdx.x)*4;
  long st = (long)gridDim.x*blockDim.x*4;
  for (; i < n; i += st){
    float4 v = *(const float4*)(src + i);
    *(ushort4*)(dst + i) = make_ushort4(f2bf(v.x), f2bf(v.y), f2bf(v.z), f2bf(v.w));
  }
}

__global__ void k_addv(const float* __restrict__ a, const float* __restrict__ b,
                       float* __restrict__ d, int n){
  int i = blockIdx.x*blockDim.x + threadIdx.x;
  if (i < n) d[i] = a[i] + b[i];
}

// cnn_w (512,512,2) -> Wconv_bf [512][1024] = [W0 | W1]
__global__ void k_repack_conv(const float* __restrict__ w, u16* __restrict__ dst){
  int i = blockIdx.x*256 + threadIdx.x;
  int o = i >> 9, ii = i & 511;
  dst[(size_t)o*1024 + ii]       = f2bf(w[((size_t)o*512 + ii)*2 + 0]);
  dst[(size_t)o*1024 + 512 + ii] = f2bf(w[((size_t)o*512 + ii)*2 + 1]);
}

// dec_Wih (4096,1536), dec_Whh (4096,1024) -> Wcat [4096][2048] = [Wih[:, :1024] | Whh], Wy [4096][512]
__global__ void k_build_wdec(const float* __restrict__ dWih, const float* __restrict__ dWhh,
                             u16* __restrict__ Wcat, u16* __restrict__ Wy){
  int r = blockIdx.x;
  for (int c = threadIdx.x; c < 1024; c += 256){
    Wcat[(size_t)r*2048 + c]        = f2bf(dWih[(size_t)r*1536 + c]);
    Wcat[(size_t)r*2048 + 1024 + c] = f2bf(dWhh[(size_t)r*1024 + c]);
  }
  for (int c = threadIdx.x; c < 512; c += 256)
    Wy[(size_t)r*512 + c] = f2bf(dWih[(size_t)r*1536 + 1024 + c]);
}

__global__ void k_gather_src(const int* __restrict__ ids, const float* __restrict__ emb,
                             u16* __restrict__ Aconv){
  int s = blockIdx.x;
  int b = blockIdx.y;
  int e = threadIdx.x*4;
  float4 v = make_float4(0.f,0.f,0.f,0.f);
  if (s < 48){ int id = ids[s*64 + b]; v = *(const float4*)(emb + (size_t)id*512 + e); }
  ushort4 u = make_ushort4(f2bf(v.x), f2bf(v.y), f2bf(v.z), f2bf(v.w));
  if (s < 48) *(ushort4*)(Aconv + ((size_t)(s*64 + b))*1024 + e) = u;
  if (s >= 1) *(ushort4*)(Aconv + ((size_t)((s-1)*64 + b))*1024 + 512 + e) = u;
}

__global__ void k_gather_y(const int* __restrict__ ids, const float* __restrict__ emb,
                           u16* __restrict__ Y){
  int t = blockIdx.x; int b = blockIdx.y; int e = threadIdx.x*4;
  int id = ids[t*64 + b];
  float4 v = *(const float4*)(emb + (size_t)id*512 + e);
  *(ushort4*)(Y + ((size_t)(t*64 + b))*512 + e) = make_ushort4(f2bf(v.x), f2bf(v.y), f2bf(v.z), f2bf(v.w));
}

// ---------------- universal MFMA GEMM (prologue / init use) ----------------
template<bool OUT_BF16, bool TANH>
__global__ __launch_bounds__(256) void k_gemm(
    const u16* __restrict__ A0, long lda0,
    const u16* __restrict__ A1, long lda1, int ksplit,
    const u16* __restrict__ W, int K,
    void* __restrict__ Out, long ldc, long out_off,
    const float* __restrict__ bias)
{
  __shared__ __align__(16) u16 As[64][72];
  __shared__ __align__(16) u16 Ws[64][72];
  const int t = threadIdx.x;
  const int m0 = blockIdx.x*64, n0 = blockIdx.y*64;
  const int w = t >> 6, l = t & 63, lr = l & 15, lh = l >> 4;
  const int sr = t >> 2, sk = (t & 3) << 4;

  f32x4 acc[4] = {{0,0,0,0},{0,0,0,0},{0,0,0,0},{0,0,0,0}};

  for (int kc = 0; kc < K; kc += 64){
    {
      const u16* wp = W + (size_t)(n0 + sr)*K + kc + sk;
      *(s16x8*)&Ws[sr][sk]     = *(const s16x8*)wp;
      *(s16x8*)&Ws[sr][sk + 8] = *(const s16x8*)(wp + 8);
    }
    {
      const u16* ap = (kc < ksplit)
        ? A0 + (size_t)(m0 + sr)*lda0 + kc
        : A1 + (size_t)(m0 + sr)*lda1 + (kc - ksplit);
      ap += sk;
      *(s16x8*)&As[sr][sk]     = *(const s16x8*)ap;
      *(s16x8*)&As[sr][sk + 8] = *(const s16x8*)(ap + 8);
    }
    __syncthreads();
    #pragma unroll
    for (int kk = 0; kk < 64; kk += 32){
      s16x8 a = *(const s16x8*)&As[w*16 + lr][kk + lh*8];
      #pragma unroll
      for (int ct = 0; ct < 4; ++ct){
        s16x8 bfr = *(const s16x8*)&Ws[ct*16 + lr][kk + lh*8];
        acc[ct] = __builtin_amdgcn_mfma_f32_16x16x32_bf16(a, bfr, acc[ct], 0, 0, 0);
      }
    }
    __syncthreads();
  }
  #pragma unroll
  for (int ct = 0; ct < 4; ++ct){
    #pragma unroll
    for (int rr = 0; rr < 4; ++rr){
      long row = m0 + w*16 + lh*4 + rr;
      long col = n0 + ct*16 + lr;
      float v = acc[ct][rr];
      if (bias) v += bias[col];
      if (TANH) v = tanhf(v);
      long oi = out_off + row*ldc + col;
      if (OUT_BF16) ((u16*)Out)[oi] = f2bf(v);
      else          ((float*)Out)[oi] = v;
    }
  }
}

// ---------------- persistent encoder ----------------
// 128 blocks: blk>>6 = dir, blk&63 -> 16 hidden units x 4 gates per block.
// Per step: fused (h @ Whh^T + G) -> LSTM activation, one grid barrier.
__global__ __launch_bounds__(256) void k_enc_persist(
    const u16* __restrict__ WhhF, const u16* __restrict__ WhhB,
    const u16* __restrict__ Gf, const u16* __restrict__ Gb,
    u16* __restrict__ hF0, u16* __restrict__ hF1,
    u16* __restrict__ hB0, u16* __restrict__ hB1,
    float* __restrict__ cF, float* __restrict__ cB,
    u16* __restrict__ Aatt, u16* __restrict__ cfbf, u16* __restrict__ cbbf,
    int* bar)
{
  __shared__ __align__(16) u16 As[64][136];
  __shared__ __align__(16) u16 Ws[64][136];
  const int t = threadIdx.x;
  const int blk = blockIdx.x;
  const int dir = blk >> 6;
  const int j0 = (blk & 63) << 4;
  const u16* W = dir ? WhhB : WhhF;
  const u16* G = dir ? Gb : Gf;
  float* c = dir ? cB : cF;
  u16* cobf = dir ? cbbf : cfbf;
  u16* h0 = dir ? hB0 : hF0;
  u16* h1 = dir ? hB1 : hF1;
  const int w = t >> 6, l = t & 63, lr = l & 15, lh = l >> 4;
  const int sr = t >> 2, sk = (t & 3) << 5;
  const int g = sr >> 4, jj = sr & 15;
  const size_t wrow = (size_t)(g*1024 + j0 + jj) * 1024;
  int gen = 0;

  for (int s = 0; s < 48; ++s){
    const u16* hin = (s & 1) ? h1 : h0;
    u16* hout      = (s & 1) ? h0 : h1;
    const int time = dir ? 47 - s : s;
    f32x4 acc[4] = {{0,0,0,0},{0,0,0,0},{0,0,0,0},{0,0,0,0}};
    for (int kc = 0; kc < 1024; kc += 128){
      const u16* wp = W + wrow + kc + sk;
      const u16* ap = hin + (size_t)sr*1024 + kc + sk;
      #pragma unroll
      for (int q = 0; q < 4; ++q){
        *(s16x8*)&Ws[sr][sk + q*8] = *(const s16x8*)(wp + q*8);
        *(s16x8*)&As[sr][sk + q*8] = *(const s16x8*)(ap + q*8);
      }
      __syncthreads();
      #pragma unroll
      for (int kk = 0; kk < 128; kk += 32){
        s16x8 a = *(const s16x8*)&As[w*16 + lr][kk + lh*8];
        #pragma unroll
        for (int ct = 0; ct < 4; ++ct){
          s16x8 bfr = *(const s16x8*)&Ws[ct*16 + lr][kk + lh*8];
          acc[ct] = __builtin_amdgcn_mfma_f32_16x16x32_bf16(a, bfr, acc[ct], 0, 0, 0);
        }
      }
      __syncthreads();
    }
    const int j = j0 + lr;
    #pragma unroll
    for (int rr = 0; rr < 4; ++rr){
      int b = w*16 + lh*4 + rr;
      size_t grow = ((size_t)time*64 + b)*4096;
      float gi = acc[0][rr] + bf2f(G[grow + j]);
      float gf = acc[1][rr] + bf2f(G[grow + 1024 + j]);
      float gg = acc[2][rr] + bf2f(G[grow + 2048 + j]);
      float go = acc[3][rr] + bf2f(G[grow + 3072 + j]);
      float cn = sigm(gf)*c[b*1024 + j] + sigm(gi)*tanhf(gg);
      float hn = sigm(go)*tanhf(cn);
      c[b*1024 + j] = cn;
      u16 hb16 = f2bf(hn);
      hout[b*1024 + j] = hb16;
      Aatt[((size_t)b*48 + time)*2048 + dir*1024 + j] = hb16;
      if (s == 47) cobf[b*1024 + j] = f2bf(cn);
    }
    if (s < 47) gbar(bar, 128, gen);
  }
}

// ---------------- persistent decoder ----------------
// 64 blocks. Per step: ph1 gates GEMM + LSTM (all blocks, 16 units x 4 gates),
// ph3 attention (block = batch row), ph5 Wcomb GEMM + tanh (blocks 0..15).
__global__ __launch_bounds__(256) void k_dec_persist(
    const u16* __restrict__ Wdec, const u16* __restrict__ Wcomb,
    const u16* __restrict__ Gy,
    u16* __restrict__ hbf0, u16* __restrict__ hbf1, float* __restrict__ cdec,
    const float* __restrict__ encproj, const u16* __restrict__ Aatt,
    u16* __restrict__ atbf, float* __restrict__ combined, u16* __restrict__ Cbf,
    const u16* __restrict__ obf_zero,
    int* bar)
{
  __shared__ __align__(16) u16 As[64][136];
  __shared__ __align__(16) u16 Ws[64][136];
  __shared__ float smax, sinv;
  const int t = threadIdx.x, blk = blockIdx.x;
  const int w = t >> 6, l = t & 63, lr = l & 15, lh = l >> 4;
  const int sr = t >> 2, sk = (t & 3) << 5;
  const int j0 = blk << 4;
  const int g = sr >> 4, jj = sr & 15;
  const size_t wrow = (size_t)(g*1024 + j0 + jj) * 2048;
  int gen = 0;
  int cur = 0;

  for (int tt = 0; tt < 47; ++tt){
    const u16* hin = cur ? hbf1 : hbf0;
    u16* hnew      = cur ? hbf0 : hbf1;
    // ---- ph1: gates = [o_prev | h] @ Wdec^T + Gy -> LSTM activation
    {
      const u16* Ao = tt ? (Cbf + (size_t)(tt - 1)*65536) : obf_zero;
      f32x4 acc[4] = {{0,0,0,0},{0,0,0,0},{0,0,0,0},{0,0,0,0}};
      for (int kc = 0; kc < 2048; kc += 128){
        const u16* ap = (kc < 1024)
          ? Ao + (size_t)sr*1024 + kc
          : hin + (size_t)sr*1024 + (kc - 1024);
        ap += sk;
        const u16* wp = Wdec + wrow + kc + sk;
        #pragma unroll
        for (int q = 0; q < 4; ++q){
          *(s16x8*)&Ws[sr][sk + q*8] = *(const s16x8*)(wp + q*8);
          *(s16x8*)&As[sr][sk + q*8] = *(const s16x8*)(ap + q*8);
        }
        __syncthreads();
        #pragma unroll
        for (int kk = 0; kk < 128; kk += 32){
          s16x8 a = *(const s16x8*)&As[w*16 + lr][kk + lh*8];
          #pragma unroll
          for (int ct = 0; ct < 4; ++ct){
            s16x8 bfr = *(const s16x8*)&Ws[ct*16 + lr][kk + lh*8];
            acc[ct] = __builtin_amdgcn_mfma_f32_16x16x32_bf16(a, bfr, acc[ct], 0, 0, 0);
          }
        }
        __syncthreads();
      }
      const int j = j0 + lr;
      #pragma unroll
      for (int rr = 0; rr < 4; ++rr){
        int b = w*16 + lh*4 + rr;
        size_t grow = ((size_t)tt*64 + b)*4096;
        float gi = acc[0][rr] + bf2f(Gy[grow + j]);
        float gf = acc[1][rr] + bf2f(Gy[grow + 1024 + j]);
        float gg = acc[2][rr] + bf2f(Gy[grow + 2048 + j]);
        float go = acc[3][rr] + bf2f(Gy[grow + 3072 + j]);
        float cn = sigm(gf)*cdec[b*1024 + j] + sigm(gi)*tanhf(gg);
        float hn = sigm(go)*tanhf(cn);
        cdec[b*1024 + j] = cn;
        hnew[b*1024 + j] = f2bf(hn);
      }
    }
    gbar(bar, 64, gen);
    // ---- ph3: attention for batch row blk
    {
      const int b = blk;
      float* hs = (float*)&As[0][0];   // 1024 f32 (4 KB, aliases As)
      float* ew = (float*)&Ws[0][0];   // 48 f32 (aliases Ws)
      for (int j = t; j < 1024; j += 256) hs[j] = bf2f(hnew[b*1024 + j]);
      __syncthreads();
      for (int s = w; s < 48; s += 4){
        const float* ep = encproj + ((size_t)b*48 + s)*1024;
        float p = 0.f;
        for (int i = l; i < 1024; i += 64) p += hs[i]*ep[i];
        for (int d = 32; d >= 1; d >>= 1) p += __shfl_xor(p, d, 64);
        if (l == 0) ew[s] = p;
      }
      __syncthreads();
      if (t == 0){
        float m = ew[0];
        for (int s = 1; s < 48; ++s) m = fmaxf(m, ew[s]);
        smax = m;
      }
      __syncthreads();
      if (t < 48) ew[t] = expf(ew[t] - smax);
      __syncthreads();
      if (t == 0){
        float su = 0.f; for (int s = 0; s < 48; ++s) su += ew[s];
        sinv = 1.0f/su;
      }
      __syncthreads();
      for (int d = t; d < 2048; d += 256){
        float accd = 0.f;
        for (int s = 0; s < 48; ++s)
          accd += ew[s]*bf2f(Aatt[((size_t)b*48 + s)*2048 + d]);
        atbf[b*2048 + d] = f2bf(accd*sinv);
      }
    }
    gbar(bar, 64, gen);
    // ---- ph5: combined = tanh([a_t | h] @ Wcomb^T), blocks 0..15
    if (blk < 16){
      const int n0 = blk << 6;
      f32x4 acc[4] = {{0,0,0,0},{0,0,0,0},{0,0,0,0},{0,0,0,0}};
      for (int kc = 0; kc < 3072; kc += 128){
        const u16* ap = (kc < 2048)
          ? atbf + (size_t)sr*2048 + kc
          : hnew + (size_t)sr*1024 + (kc - 2048);
        ap += sk;
        const u16* wp = Wcomb + (size_t)(n0 + sr)*3072 + kc + sk;
        #pragma unroll
        for (int q = 0; q < 4; ++q){
          *(s16x8*)&Ws[sr][sk + q*8] = *(const s16x8*)(wp + q*8);
          *(s16x8*)&As[sr][sk + q*8] = *(const s16x8*)(ap + q*8);
        }
        __syncthreads();
        #pragma unroll
        for (int kk = 0; kk < 128; kk += 32){
          s16x8 a = *(const s16x8*)&As[w*16 + lr][kk + lh*8];
          #pragma unroll
          for (int ct = 0; ct < 4; ++ct){
            s16x8 bfr = *(const s16x8*)&Ws[ct*16 + lr][kk + lh*8];
            acc[ct] = __builtin_amdgcn_mfma_f32_16x16x32_bf16(a, bfr, acc[ct], 0, 0, 0);
          }
        }
        __syncthreads();
      }
      #pragma unroll
      for (int ct = 0; ct < 4; ++ct){
        #pragma unroll
        for (int rr = 0; rr < 4; ++rr){
          int row = w*16 + lh*4 + rr;
          int col = n0 + ct*16 + lr;
          float v = tanhf(acc[ct][rr]);
          size_t oi = (size_t)tt*65536 + (size_t)row*1024 + col;
          combined[oi] = v;
          Cbf[oi] = f2bf(v);
        }
      }
    }
    gbar(bar, 64, gen);
    cur ^= 1;
  }
}

// ---------------- fused vocab GEMM + online logsumexp ----------------
#define VNS 25
__global__ __launch_bounds__(256) void k_vocab_lse(
    const u16* __restrict__ Cbf, const u16* __restrict__ Wv, float2* __restrict__ partials)
{
  __shared__ __align__(16) u16 As[64][136];
  __shared__ __align__(16) u16 Ws[64][136];
  int rb = blockIdx.x, sp = blockIdx.y;
  int m0 = rb*64;
  int t = threadIdx.x, w = t >> 6, l = t & 63, lr = l & 15, lh = l >> 4;
  int sr = t >> 2, sk = (t & 3) << 5;
  float mrun[4] = {-INFINITY, -INFINITY, -INFINITY, -INFINITY};
  float srun[4] = {0.f, 0.f, 0.f, 0.f};

  for (int nt = 0; nt < 20; ++nt){
    int n0 = sp*1280 + nt*64;
    f32x4 acc[4] = {{0,0,0,0},{0,0,0,0},{0,0,0,0},{0,0,0,0}};
    for (int kc = 0; kc < 1024; kc += 128){
      const u16* ap = Cbf + (size_t)(m0 + sr)*1024 + kc + sk;
      const u16* wp = Wv  + (size_t)(n0 + sr)*1024 + kc + sk;
      #pragma unroll
      for (int q = 0; q < 4; ++q){
        *(s16x8*)&As[sr][sk + q*8] = *(const s16x8*)(ap + q*8);
        *(s16x8*)&Ws[sr][sk + q*8] = *(const s16x8*)(wp + q*8);
      }
      __syncthreads();
      #pragma unroll
      for (int kk = 0; kk < 128; kk += 32){
        s16x8 a = *(const s16x8*)&As[w*16 + lr][kk + lh*8];
        #pragma unroll
        for (int ct = 0; ct < 4; ++ct){
          s16x8 bfr = *(const s16x8*)&Ws[ct*16 + lr][kk + lh*8];
          acc[ct] = __builtin_amdgcn_mfma_f32_16x16x32_bf16(a, bfr, acc[ct], 0, 0, 0);
        }
      }
      __syncthreads();
    }
    #pragma unroll
    for (int rr = 0; rr < 4; ++rr){
      float tm = fmaxf(fmaxf(acc[0][rr], acc[1][rr]), fmaxf(acc[2][rr], acc[3][rr]));
      for (int d = 1; d < 16; d <<= 1) tm = fmaxf(tm, __shfl_xor(tm, d, 64));
      float ts = expf(acc[0][rr] - tm) + expf(acc[1][rr] - tm)
               + expf(acc[2][rr] - tm) + expf(acc[3][rr] - tm);
      for (int d = 1; d < 16; d <<= 1) ts += __shfl_xor(ts, d, 64);
      if (tm > mrun[rr]){ srun[rr] = srun[rr]*expf(mrun[rr] - tm) + ts; mrun[rr] = tm; }
      else srun[rr] += ts*expf(tm - mrun[rr]);
    }
  }
  if (lr == 0){
    #pragma unroll
    for (int rr = 0; rr < 4; ++rr){
      long row = m0 + w*16 + lh*4 + rr;
      partials[row*VNS + sp] = make_float2(mrun[rr], srun[rr]);
    }
  }
}

__global__ void k_lse(const float2* __restrict__ partials, float* __restrict__ lse){
  int r = blockIdx.x*256 + threadIdx.x;
  if (r >= 3008) return;
  float m = -INFINITY, s = 0.f;
  for (int i = 0; i < VNS; ++i){
    float2 p = partials[r*VNS + i];
    if (p.x > m){ s = s*expf(m - p.x) + p.y; m = p.x; }
    else s += p.y*expf(p.x - m);
  }
  lse[r] = m + logf(s);
}

__global__ __launch_bounds__(256) void k_gold(const float* __restrict__ combined,
                                              const float* __restrict__ Wv,
                                              const int* __restrict__ tgt,
                                              float* __restrict__ gold){
  int w = threadIdx.x >> 6, l = threadIdx.x & 63;
  int r = blockIdx.x*4 + w;
  int tt = r >> 6, b = r & 63;
  int gid = tgt[(tt + 1)*64 + b];
  const float* cp = combined + (size_t)r*1024;
  const float* wp = Wv + (size_t)gid*1024;
  float p = 0.f;
  for (int i = l; i < 1024; i += 64) p += cp[i]*wp[i];
  for (int d = 32; d >= 1; d >>= 1) p += __shfl_xor(p, d, 64);
  if (l == 0) gold[r] = p;
}

__global__ void k_final(const float* __restrict__ gold, const float* __restrict__ lse,
                        const int* __restrict__ tgt, float* __restrict__ out){
  int b = threadIdx.x;
  if (b >= 64) return;
  float acc = 0.f;
  for (int t = 0; t < 47; ++t){
    int gid = tgt[(t + 1)*64 + b];
    if (gid != 0) acc += gold[t*64 + b] - lse[t*64 + b];
  }
  out[b] = acc;
}

// ---------------- host ----------------
extern "C" void kernel_launch(void* const* d_in, const int* in_sizes, int n_in,
                              void* d_out, int out_size, void* d_ws, size_t ws_size,
                              hipStream_t stream)
{
  (void)in_sizes; (void)n_in; (void)out_size; (void)ws_size;
  const int*   src_ids = (const int*)d_in[0];
  const int*   tgt_ids = (const int*)d_in[1];
  const float* src_emb = (const float*)d_in[3];
  const float* tgt_emb = (const float*)d_in[4];
  const float* cnn_w   = (const float*)d_in[5];
  const float* cnn_b   = (const float*)d_in[6];
  const float* eWih_f  = (const float*)d_in[7];
  const float* eWhh_f  = (const float*)d_in[8];
  const float* ebih_f  = (const float*)d_in[9];
  const float* ebhh_f  = (const float*)d_in[10];
  const float* eWih_b  = (const float*)d_in[11];
  const float* eWhh_b  = (const float*)d_in[12];
  const float* ebih_b  = (const float*)d_in[13];
  const float* ebhh_b  = (const float*)d_in[14];
  const float* dWih    = (const float*)d_in[15];
  const float* dWhh    = (const float*)d_in[16];
  const float* dbih    = (const float*)d_in[17];
  const float* dbhh    = (const float*)d_in[18];
  const float* Wh      = (const float*)d_in[19];
  const float* Wc      = (const float*)d_in[20];
  const float* Watt    = (const float*)d_in[21];
  const float* Wcomb   = (const float*)d_in[22];
  const float* Wvocab  = (const float*)d_in[23];

  char* ws = (char*)d_ws;
  size_t off = 0;
  auto alloc = [&](size_t bytes)->char*{
    char* p = ws + off;
    off = (off + bytes + 255) & ~(size_t)255;
    return p;
  };

  // --- zero region (contiguous, re-zeroed every launch) ---
  u16* hF0      = (u16*)alloc((size_t)65536*2);
  u16* hF1      = (u16*)alloc((size_t)65536*2);
  u16* hB0      = (u16*)alloc((size_t)65536*2);
  u16* hB1      = (u16*)alloc((size_t)65536*2);
  float* cF     = (float*)alloc((size_t)65536*4);
  float* cB     = (float*)alloc((size_t)65536*4);
  u16* obf_zero = (u16*)alloc((size_t)65536*2);
  int* bar      = (int*)alloc(256);
  size_t zero_floats = ((size_t)65536*2*5 + (size_t)65536*4*2 + 256)/4;

  // --- weights (bf16) ---
  u16* Wconv_bf = (u16*)alloc((size_t)512*1024*2);
  u16* Wih_f_bf = (u16*)alloc((size_t)4096*512*2);
  u16* Wih_b_bf = (u16*)alloc((size_t)4096*512*2);
  u16* Whh_f_bf = (u16*)alloc((size_t)4096*1024*2);
  u16* Whh_b_bf = (u16*)alloc((size_t)4096*1024*2);
  u16* Wdec_bf  = (u16*)alloc((size_t)4096*2048*2);
  u16* WdecY_bf = (u16*)alloc((size_t)4096*512*2);
  u16* Wh_bf    = (u16*)alloc((size_t)1024*2048*2);
  u16* Wc_bf    = (u16*)alloc((size_t)1024*2048*2);
  u16* Watt_bf  = (u16*)alloc((size_t)1024*2048*2);
  u16* Wcomb_bf = (u16*)alloc((size_t)1024*3072*2);
  u16* Wv_bf    = (u16*)alloc((size_t)32000*1024*2);
  float* benc_f = (float*)alloc(4096*4);
  float* benc_b = (float*)alloc(4096*4);
  float* bdec   = (float*)alloc(4096*4);

  // --- activations ---
  u16* Aconv    = (u16*)alloc((size_t)3072*1024*2);
  u16* Xc       = (u16*)alloc((size_t)3072*512*2);
  u16* Gf       = (u16*)alloc((size_t)3072*4096*2);
  u16* Gb       = (u16*)alloc((size_t)3072*4096*2);
  u16* Ybf      = (u16*)alloc((size_t)3008*512*2);
  u16* Gy       = (u16*)alloc((size_t)3008*4096*2);
  u16* Aatt     = (u16*)alloc((size_t)3072*2048*2);
  float* encproj= (float*)alloc((size_t)3072*1024*4);
  u16* cfbf     = (u16*)alloc((size_t)65536*2);
  u16* cbbf     = (u16*)alloc((size_t)65536*2);
  float* hdec0  = (float*)alloc((size_t)65536*4);
  u16* hbf0     = (u16*)alloc((size_t)65536*2);
  u16* hbf1     = (u16*)alloc((size_t)65536*2);
  float* cdec   = (float*)alloc((size_t)65536*4);
  u16* atbf     = (u16*)alloc((size_t)64*2048*2);
  float* combined=(float*)alloc((size_t)3008*1024*4);
  u16* Cbf      = (u16*)alloc((size_t)3008*1024*2);
  float2* partials=(float2*)alloc((size_t)3008*VNS*8);
  float* lse    = (float*)alloc(3008*4);
  float* gold   = (float*)alloc(3008*4);

  k_zero<<<288, 256, 0, stream>>>((float*)hF0, (long)zero_floats);

  auto cgrid = [](long n)->int{ long g = (n/4 + 255)/256; return (int)(g > 1024 ? 1024 : g); };
  k_cast_bf16<<<cgrid(4096*512), 256, 0, stream>>>(eWih_f, Wih_f_bf, (long)4096*512);
  k_cast_bf16<<<cgrid(4096*512), 256, 0, stream>>>(eWih_b, Wih_b_bf, (long)4096*512);
  k_cast_bf16<<<cgrid(4096*1024), 256, 0, stream>>>(eWhh_f, Whh_f_bf, (long)4096*1024);
  k_cast_bf16<<<cgrid(4096*1024), 256, 0, stream>>>(eWhh_b, Whh_b_bf, (long)4096*1024);
  k_cast_bf16<<<cgrid(1024*2048), 256, 0, stream>>>(Wh, Wh_bf, (long)1024*2048);
  k_cast_bf16<<<cgrid(1024*2048), 256, 0, stream>>>(Wc, Wc_bf, (long)1024*2048);
  k_cast_bf16<<<cgrid(1024*2048), 256, 0, stream>>>(Watt, Watt_bf, (long)1024*2048);
  k_cast_bf16<<<cgrid(1024*3072), 256, 0, stream>>>(Wcomb, Wcomb_bf, (long)1024*3072);
  k_cast_bf16<<<cgrid((long)32000*1024), 256, 0, stream>>>(Wvocab, Wv_bf, (long)32000*1024);

  k_addv<<<16, 256, 0, stream>>>(ebih_f, ebhh_f, benc_f, 4096);
  k_addv<<<16, 256, 0, stream>>>(ebih_b, ebhh_b, benc_b, 4096);
  k_addv<<<16, 256, 0, stream>>>(dbih, dbhh, bdec, 4096);

  k_repack_conv<<<1024, 256, 0, stream>>>(cnn_w, Wconv_bf);
  k_build_wdec<<<4096, 256, 0, stream>>>(dWih, dWhh, Wdec_bf, WdecY_bf);

  k_gather_src<<<dim3(49, 64), 128, 0, stream>>>(src_ids, src_emb, Aconv);
  k_gather_y<<<dim3(47, 64), 128, 0, stream>>>(tgt_ids, tgt_emb, Ybf);

  // conv: Xc = Aconv @ Wconv^T + cnn_b (bf16 out)
  k_gemm<true, false><<<dim3(48, 8), 256, 0, stream>>>(
      Aconv, 1024, Aconv, 1024, 1024, Wconv_bf, 1024, Xc, 512, 0, cnn_b);
  // input-gate precomputes (include both biases)
  k_gemm<true, false><<<dim3(48, 64), 256, 0, stream>>>(
      Xc, 512, Xc, 512, 512, Wih_f_bf, 512, Gf, 4096, 0, benc_f);
  k_gemm<true, false><<<dim3(48, 64), 256, 0, stream>>>(
      Xc, 512, Xc, 512, 512, Wih_b_bf, 512, Gb, 4096, 0, benc_b);
  k_gemm<true, false><<<dim3(47, 64), 256, 0, stream>>>(
      Ybf, 512, Ybf, 512, 512, WdecY_bf, 512, Gy, 4096, 0, bdec);

  // persistent bidirectional encoder (48 steps, 1 barrier/step)
  k_enc_persist<<<128, 256, 0, stream>>>(
      Whh_f_bf, Whh_b_bf, Gf, Gb, hF0, hF1, hB0, hB1, cF, cB,
      Aatt, cfbf, cbbf, bar);

  // decoder init: dec_h = [hf|hb]@Wh^T ; dec_c = [cf|cb]@Wc^T (c-state fix)
  k_gemm<false, false><<<dim3(1, 16), 256, 0, stream>>>(
      hF0, 1024, hB0, 1024, 1024, Wh_bf, 2048, hdec0, 1024, 0, nullptr);
  k_cast_bf16<<<64, 256, 0, stream>>>(hdec0, hbf0, (long)65536);
  k_gemm<false, false><<<dim3(1, 16), 256, 0, stream>>>(
      cfbf, 1024, cbbf, 1024, 1024, Wc_bf, 2048, cdec, 1024, 0, nullptr);
  // enc_proj = enc_hiddens @ Watt^T (f32)
  k_gemm<false, false><<<dim3(48, 16), 256, 0, stream>>>(
      Aatt, 2048, Aatt, 2048, 2048, Watt_bf, 2048, encproj, 1024, 0, nullptr);

  // persistent decoder (47 steps, 3 barriers/step)
  k_dec_persist<<<64, 256, 0, stream>>>(
      Wdec_bf, Wcomb_bf, Gy, hbf0, hbf1, cdec, encproj, Aatt,
      atbf, combined, Cbf, obf_zero, bar + 1);

  // vocab logsumexp + gold + final
  k_vocab_lse<<<dim3(47, VNS), 256, 0, stream>>>(Cbf, Wv_bf, partials);
  k_lse<<<12, 256, 0, stream>>>(partials, lse);
  k_gold<<<752, 256, 0, stream>>>(combined, Wvocab, tgt_ids, gold);
  k_final<<<1, 64, 0, stream>>>(gold, lse, tgt_ids, (float*)d_out);
}